// Round 2
// baseline (47750.290 us; speedup 1.0000x reference)
//
#include <hip/hip_runtime.h>

// Problem constants
#define T_STEPS 16384
#define TC      8192     // time chunk for Z staging (2 chunks)
#define DMODEL  1024
#define HID     512      // per-direction hidden
#define G4      2048     // 4*HID gate rows
#define NC      16

// ---------------- ws layout (fits 256 MiB) ----------------
// floats:
//   Zf [TC*2048], Zb [TC*2048], hf [T*512], hb [T*512], feats [T*16], c_state[2*512]
// bytes after:
//   bp u8[T*16], P u8[64*256*16], ex u64[2dir*2par*512], bT u32
static const unsigned long long OFF_ZF    = 0ull;                    // 16,777,216 f
static const unsigned long long OFF_ZB    = 16777216ull;             // 16,777,216 f
static const unsigned long long OFF_HF    = 33554432ull;             //  8,388,608 f
static const unsigned long long OFF_HB    = 41943040ull;             //  8,388,608 f
static const unsigned long long OFF_FEATS = 50331648ull;             //    262,144 f
static const unsigned long long OFF_CST   = 50593792ull;             //      1,024 f
static const unsigned long long FLOATS_TOTAL = 50594816ull;
static const unsigned long long OFF_BP_B = FLOATS_TOTAL * 4ull;      // 202,379,264
static const unsigned long long OFF_P_B  = OFF_BP_B + 262144ull;
static const unsigned long long OFF_EX_B = OFF_P_B + 262144ull;
static const unsigned long long OFF_BT_B = OFF_EX_B + 16384ull;
static const unsigned long long NEED_B   = OFF_BT_B + 64ull;         // ~202.9 MB

// =====================================================================
// Kernel A: Z[r] = X[t0+r] @ W_ih^T + (b_ih + b_hh), chunk rows r in [0,TC)
// fp32, 64x64 tile, BK=16
// =====================================================================
__global__ __launch_bounds__(256) void zgemm_kernel(
    const float* __restrict__ X,
    const float* __restrict__ W0, const float* __restrict__ bi0,
    const float* __restrict__ bh0, float* __restrict__ Z0, int t00,
    const float* __restrict__ W1, const float* __restrict__ bi1,
    const float* __restrict__ bh1, float* __restrict__ Z1, int t01)
{
    const int dir = blockIdx.z;
    const float* W  = dir ? W1 : W0;
    const float* bi = dir ? bi1 : bi0;
    const float* bh = dir ? bh1 : bh0;
    float* Z        = dir ? Z1 : Z0;
    const int t0    = dir ? t01 : t00;

    const int m0 = blockIdx.y * 64;   // chunk-local t tile
    const int n0 = blockIdx.x * 64;   // gate-row tile

    __shared__ __align__(16) float As[16][68];
    __shared__ __align__(16) float Bs[16][68];

    const int tid = threadIdx.x;
    const int lr = tid >> 2;          // 0..63 tile row (staging)
    const int ls = tid & 3;           // k segment
    const int tx = tid & 15;
    const int ty = tid >> 4;

    float acc[4][4] = {};

    for (int k0 = 0; k0 < DMODEL; k0 += 16) {
        float4 av = *(const float4*)&X[(unsigned long long)(t0 + m0 + lr) * DMODEL + k0 + ls * 4];
        float4 bv = *(const float4*)&W[(unsigned long long)(n0 + lr) * DMODEL + k0 + ls * 4];
        __syncthreads();
        As[ls*4+0][lr] = av.x; As[ls*4+1][lr] = av.y; As[ls*4+2][lr] = av.z; As[ls*4+3][lr] = av.w;
        Bs[ls*4+0][lr] = bv.x; Bs[ls*4+1][lr] = bv.y; Bs[ls*4+2][lr] = bv.z; Bs[ls*4+3][lr] = bv.w;
        __syncthreads();
        #pragma unroll
        for (int k = 0; k < 16; ++k) {
            float4 a = *(const float4*)&As[k][ty * 4];
            float4 b = *(const float4*)&Bs[k][tx * 4];
            acc[0][0] += a.x*b.x; acc[0][1] += a.x*b.y; acc[0][2] += a.x*b.z; acc[0][3] += a.x*b.w;
            acc[1][0] += a.y*b.x; acc[1][1] += a.y*b.y; acc[1][2] += a.y*b.z; acc[1][3] += a.y*b.w;
            acc[2][0] += a.z*b.x; acc[2][1] += a.z*b.y; acc[2][2] += a.z*b.z; acc[2][3] += a.z*b.w;
            acc[3][0] += a.w*b.x; acc[3][1] += a.w*b.y; acc[3][2] += a.w*b.z; acc[3][3] += a.w*b.w;
        }
    }
    float4 bi4 = *(const float4*)&bi[n0 + tx * 4];
    float4 bh4 = *(const float4*)&bh[n0 + tx * 4];
    float bx = bi4.x + bh4.x, by = bi4.y + bh4.y, bz = bi4.z + bh4.z, bw = bi4.w + bh4.w;
    #pragma unroll
    for (int i = 0; i < 4; ++i) {
        float4 o;
        o.x = acc[i][0] + bx; o.y = acc[i][1] + by; o.z = acc[i][2] + bz; o.w = acc[i][3] + bw;
        *(float4*)&Z[(unsigned long long)(m0 + ty * 4 + i) * G4 + n0 + tx * 4] = o;
    }
}

// =====================================================================
// Kernel B: recurrence chunk [s0, s0+TC). 64 WGs x 256 thr.
// WG = (dir,g): dir = wg>>5. WG g owns units [16g,16g+16):
// gate rows R = 512*G + 16g + u, G=0..3. Wave w holds K-chunk
// [128w,128w+128) of its lane's W_hh row in VGPRs.
// h exchanged via u64 {tag(s+1) | f32 h} relaxed agent atomics,
// double-buffered by tag parity.
// =====================================================================
__global__ __launch_bounds__(256, 1) void recur_kernel(
    const float* __restrict__ Zf, const float* __restrict__ Zb,
    const float* __restrict__ whh_f, const float* __restrict__ whh_b,
    const float* __restrict__ h0, const float* __restrict__ c0,
    float* __restrict__ hf, float* __restrict__ hb,
    unsigned long long* __restrict__ exf, unsigned long long* __restrict__ exb,
    float* __restrict__ c_state, int s0, int zf_t0, int zb_t0)
{
    const int wg  = blockIdx.x;
    const int dir = wg >> 5;
    const int g   = wg & 31;
    const float* Z   = dir ? Zb : Zf;
    const float* whh = dir ? whh_b : whh_f;
    float* hout      = dir ? hb : hf;
    const int zt0    = dir ? zb_t0 : zf_t0;
    unsigned long long* ex = dir ? exb : exf;

    const int tid  = threadIdx.x;
    const int w    = tid >> 6;     // wave = K chunk
    const int lane = tid & 63;
    const int G    = lane >> 4;
    const int u    = lane & 15;
    const int R    = 512 * G + 16 * g + u;

    float wreg[128];
    {
        const float* src = &whh[(unsigned long long)R * HID + w * 128];
        #pragma unroll
        for (int j4 = 0; j4 < 32; ++j4) {
            float4 v = *(const float4*)&src[j4 * 4];
            wreg[j4*4+0] = v.x; wreg[j4*4+1] = v.y; wreg[j4*4+2] = v.z; wreg[j4*4+3] = v.w;
        }
    }

    __shared__ __align__(16) float h_lds[512];
    __shared__ __align__(16) float p_lds[256];

    float cst = 0.0f;
    if (w == 0 && lane < 16)
        cst = (s0 == 0) ? c0[dir * HID + 16 * g + lane]
                        : c_state[dir * HID + 16 * g + lane];

    for (int s = s0; s < s0 + TC; ++s) {
        const int t = dir ? (T_STEPS - 1 - s) : s;
        float zr = 0.0f;
        if (w == 0) zr = Z[(unsigned long long)(t - zt0) * G4 + R];   // early issue

        int dead = 0;
        if (s == 0) {
            h_lds[2*tid]   = h0[dir * HID + 2*tid];
            h_lds[2*tid+1] = h0[dir * HID + 2*tid + 1];
        } else {
            const int par = s & 1;
            const unsigned long long want = (unsigned long long)s;
            #pragma unroll
            for (int r = 0; r < 2; ++r) {
                const int idx = 2 * tid + r;
                unsigned long long v;
                int guard = 0;
                do {
                    v = __hip_atomic_load(&ex[par * 512 + idx], __ATOMIC_RELAXED,
                                          __HIP_MEMORY_SCOPE_AGENT);
                    if (++guard >= (1 << 17)) { dead = 1; break; }
                } while ((v >> 32) != want);
                union { unsigned int ui; float f; } cv;
                cv.ui = (unsigned int)v;
                h_lds[idx] = cv.f;
            }
        }
        if (__syncthreads_or(dead)) break;   // barrier 1 (+ abort path, no hang)

        float acc = 0.0f;
        const float4* h4 = (const float4*)&h_lds[w * 128];
        #pragma unroll
        for (int c4 = 0; c4 < 32; ++c4) {
            float4 hv = h4[c4];
            acc += wreg[c4*4+0]*hv.x + wreg[c4*4+1]*hv.y
                 + wreg[c4*4+2]*hv.z + wreg[c4*4+3]*hv.w;
        }
        p_lds[tid] = acc;
        __syncthreads();                     // barrier 2

        if (w == 0) {
            float rv = p_lds[lane] + p_lds[64+lane] + p_lds[128+lane] + p_lds[192+lane] + zr;
            float iv = __shfl(rv, u,      64);
            float fv = __shfl(rv, u + 16, 64);
            float gv = __shfl(rv, u + 32, 64);
            float ov = __shfl(rv, u + 48, 64);
            if (lane < 16) {
                float ig = 1.0f / (1.0f + expf(-iv));
                float fg = 1.0f / (1.0f + expf(-fv));
                float gg = tanhf(gv);
                float og = 1.0f / (1.0f + expf(-ov));
                float cn = fg * cst + ig * gg;
                float hn = og * tanhf(cn);
                cst = cn;
                hout[(unsigned long long)t * HID + 16 * g + lane] = hn;
                union { float f; unsigned int ui; } cv; cv.f = hn;
                unsigned long long pv = ((unsigned long long)(s + 1) << 32) | (unsigned long long)cv.ui;
                __hip_atomic_store(&ex[((s + 1) & 1) * 512 + 16 * g + lane], pv,
                                   __ATOMIC_RELAXED, __HIP_MEMORY_SCOPE_AGENT);
            }
        }
        __syncthreads();                     // barrier 3
    }

    if (w == 0 && lane < 16)
        c_state[dir * HID + 16 * g + lane] = cst;   // carry c across chunks
}

// =====================================================================
// Kernel C: feats[t][c] = dot(hf[t]||hb[t], w_lin[c]) + b_lin[c]
// =====================================================================
__global__ __launch_bounds__(256) void feats_kernel(
    const float* __restrict__ hf, const float* __restrict__ hb,
    const float* __restrict__ wlin, const float* __restrict__ blin,
    float* __restrict__ feats)
{
    const int t = blockIdx.x;
    __shared__ __align__(16) float hl[1024];
    const int tid = threadIdx.x;
    {
        const float* src = (tid < 128) ? &hf[(unsigned long long)t * HID + tid * 4]
                                       : &hb[(unsigned long long)t * HID + (tid - 128) * 4];
        *(float4*)&hl[tid * 4] = *(const float4*)src;
    }
    __syncthreads();
    const int c = tid >> 4, p = tid & 15;
    float s = 0.0f;
    #pragma unroll
    for (int j = 0; j < 16; ++j) {
        float4 h4 = *(const float4*)&hl[p * 4 + j * 64];
        float4 w4 = *(const float4*)&wlin[(unsigned long long)c * 1024 + p * 4 + j * 64];
        s += h4.x*w4.x + h4.y*w4.y + h4.z*w4.z + h4.w*w4.w;
    }
    s += __shfl_down(s, 8, 16);
    s += __shfl_down(s, 4, 16);
    s += __shfl_down(s, 2, 16);
    s += __shfl_down(s, 1, 16);
    if (p == 0) feats[t * NC + c] = s + blin[c];
}

// =====================================================================
// Kernel D: Viterbi forward, single wave. fv kept in registers,
// broadcast via shfl (no wave-synchronous LDS). bp u8[T][16] to global.
// =====================================================================
__global__ __launch_bounds__(64) void viterbi_kernel(
    const float* __restrict__ feats, const float* __restrict__ trans,
    unsigned char* __restrict__ bp, float* __restrict__ out,
    unsigned int* __restrict__ bT)
{
    __shared__ __align__(16) float fl[4096];
    __shared__ __align__(16) float fvs[16];
    const int l = threadIdx.x;
    float tr[16];
    if (l < 16) {
        #pragma unroll
        for (int j = 0; j < 16; ++j) tr[j] = trans[l * 16 + j];
    }
    float fv = 0.0f;   // forward_var starts at zeros
    for (int cb = 0; cb < 64; ++cb) {
        #pragma unroll
        for (int j = 0; j < 16; ++j)
            *(float4*)&fl[j * 256 + l * 4] =
                *(const float4*)&feats[cb * 4096 + j * 256 + l * 4];
        __syncthreads();
        if (l < 16) {
            for (int k = 0; k < 256; ++k) {
                float m = __shfl(fv, 0, 16) + tr[0];
                int bi = 0;
                #pragma unroll
                for (int j = 1; j < 16; ++j) {
                    float sc = __shfl(fv, j, 16) + tr[j];
                    if (sc > m) { m = sc; bi = j; }   // strict > => first max (np.argmax)
                }
                bp[(unsigned long long)(cb * 256 + k) * 16 + l] = (unsigned char)bi;
                fv = m + fl[k * 16 + l];
            }
        }
        __syncthreads();
    }
    if (l < 16) fvs[l] = fv;
    __syncthreads();
    if (l == 0) {
        float best = fvs[0]; int bi = 0;
        #pragma unroll
        for (int j = 1; j < 16; ++j) if (fvs[j] > best) { best = fvs[j]; bi = j; }
        out[0] = best;
        out[1 + T_STEPS] = (float)bi;
        *bT = (unsigned int)bi;
    }
}

// =====================================================================
// Kernel E: per-block composed backpointer maps.
// P[j][k][s] = state at step j*256+k given state at block-(j) end is s.
// =====================================================================
__global__ __launch_bounds__(64) void maps_kernel(
    const unsigned char* __restrict__ bp, unsigned char* __restrict__ P)
{
    const int j = blockIdx.x;
    const int l = threadIdx.x;
    __shared__ __align__(16) unsigned char lb[4096];
    __shared__ __align__(16) unsigned char lp[4096];
    #pragma unroll
    for (int i = 0; i < 4; ++i)
        *(uint4*)&lb[i * 1024 + l * 16] = *(const uint4*)&bp[(unsigned long long)j * 4096 + i * 1024 + l * 16];
    __syncthreads();
    if (l < 16) {
        int cur = l;
        for (int k = 255; k >= 0; --k) {
            cur = lb[k * 16 + cur];
            lp[k * 16 + l] = (unsigned char)cur;
        }
    }
    __syncthreads();
    #pragma unroll
    for (int i = 0; i < 4; ++i)
        *(uint4*)&P[(unsigned long long)j * 4096 + i * 1024 + l * 16] = *(const uint4*)&lp[i * 1024 + l * 16];
}

// =====================================================================
// Kernel F: stitch + write path as float. Block j chains block maps
// 63..j+1 for its entry state, then gathers its 256 entries.
// =====================================================================
__global__ __launch_bounds__(64) void path_kernel(
    const unsigned char* __restrict__ P, const unsigned int* __restrict__ bT,
    float* __restrict__ out)
{
    const int j = blockIdx.x;
    const int l = threadIdx.x;
    int e = (int)(*bT);
    for (int i = 63; i > j; --i) e = P[(unsigned long long)i * 4096 + e];
    for (int k = l; k < 256; k += 64)
        out[1 + j * 256 + k] = (float)P[(unsigned long long)j * 4096 + k * 16 + e];
}

// fallback if ws too small: encode ws_size in the score slot for diagnosis
__global__ void fb_kernel(float* out, int n, float v0) {
    int i = blockIdx.x * 256 + threadIdx.x;
    if (i < n) out[i] = (i == 0) ? v0 : 0.0f;
}

extern "C" void kernel_launch(void* const* d_in, const int* in_sizes, int n_in,
                              void* d_out, int out_size, void* d_ws, size_t ws_size,
                              hipStream_t stream) {
    const float* seq   = (const float*)d_in[0];
    const float* h0    = (const float*)d_in[1];
    const float* c0    = (const float*)d_in[2];
    const float* wih_f = (const float*)d_in[3];
    const float* whh_f = (const float*)d_in[4];
    const float* bih_f = (const float*)d_in[5];
    const float* bhh_f = (const float*)d_in[6];
    const float* wih_b = (const float*)d_in[7];
    const float* whh_b = (const float*)d_in[8];
    const float* bih_b = (const float*)d_in[9];
    const float* bhh_b = (const float*)d_in[10];
    const float* wlin  = (const float*)d_in[11];
    const float* blin  = (const float*)d_in[12];
    const float* trans = (const float*)d_in[13];
    float* out = (float*)d_out;

    if (ws_size < NEED_B) {
        fb_kernel<<<(out_size + 255) / 256, 256, 0, stream>>>(out, out_size, -(float)ws_size);
        return;
    }

    float* wsf = (float*)d_ws;
    float* Zf    = wsf + OFF_ZF;
    float* Zb    = wsf + OFF_ZB;
    float* hf    = wsf + OFF_HF;
    float* hb    = wsf + OFF_HB;
    float* feats = wsf + OFF_FEATS;
    float* cstate= wsf + OFF_CST;
    unsigned char* bp = (unsigned char*)d_ws + OFF_BP_B;
    unsigned char* P  = (unsigned char*)d_ws + OFF_P_B;
    unsigned long long* exf = (unsigned long long*)((char*)d_ws + OFF_EX_B);
    unsigned long long* exb = exf + 1024;
    unsigned int* bT = (unsigned int*)((char*)d_ws + OFF_BT_B);

    // clear exchange tags so polls never match stale values from a prior call
    hipMemsetAsync((void*)exf, 0, 16384, stream);

    for (int ci = 0; ci < 2; ++ci) {
        int s0    = ci * TC;
        int zf_t0 = ci * TC;                    // forward chunk covers t in [s0, s0+TC)
        int zb_t0 = T_STEPS - (ci + 1) * TC;    // backward chunk covers t in [T-(ci+1)TC, T-ci*TC)

        zgemm_kernel<<<dim3(32, TC / 64, 2), 256, 0, stream>>>(
            seq, wih_f, bih_f, bhh_f, Zf, zf_t0, wih_b, bih_b, bhh_b, Zb, zb_t0);

        void* args[] = { (void*)&Zf, (void*)&Zb, (void*)&whh_f, (void*)&whh_b,
                         (void*)&h0, (void*)&c0, (void*)&hf, (void*)&hb,
                         (void*)&exf, (void*)&exb, (void*)&cstate,
                         (void*)&s0, (void*)&zf_t0, (void*)&zb_t0 };
        hipError_t e = hipLaunchCooperativeKernel(
            reinterpret_cast<void*>(recur_kernel), dim3(64), dim3(256),
            args, 0, stream);
        if (e != hipSuccess) {
            recur_kernel<<<64, 256, 0, stream>>>(Zf, Zb, whh_f, whh_b, h0, c0,
                                                 hf, hb, exf, exb, cstate,
                                                 s0, zf_t0, zb_t0);
        }
    }

    feats_kernel<<<16384, 256, 0, stream>>>(hf, hb, wlin, blin, feats);
    viterbi_kernel<<<1, 64, 0, stream>>>(feats, trans, bp, out, bT);
    maps_kernel<<<64, 64, 0, stream>>>(bp, P);
    path_kernel<<<64, 64, 0, stream>>>(P, bT, out);
}

// Round 3
// 43744.293 us; speedup vs baseline: 1.0916x; 1.0916x over previous
//
#include <hip/hip_runtime.h>

// Problem constants
#define T_STEPS 16384
#define CSTEPS  1024     // steps per Z chunk
#define NCHUNK  16
#define DMODEL  1024
#define HID     512      // per-direction hidden
#define G4      2048     // 4*HID gate rows
#define NC      16
#define NGEMMB  192      // GEMM producer blocks

// ---------------- ws layout ----------------
// floats: Zbuf[4][1024][2048] (dir*2+par), hf[T*512], hb[T*512], feats[T*16]
// bytes:  bp u8[T*16], P u8[64*256*16], ex u64[2*1024], counters
static const size_t OFF_Z     = 0;             // 8,388,608 floats (32 MB)
static const size_t OFF_HF    = 8388608ull;    // 8,388,608 floats
static const size_t OFF_HB    = 16777216ull;
static const size_t OFF_FEATS = 25165824ull;   // 262,144 floats
static const size_t FLOATS_TOTAL = 25427968ull;
static const size_t OFF_BP_B  = FLOATS_TOTAL * 4ull;   // 101,711,872
static const size_t OFF_P_B   = OFF_BP_B + 262144ull;
static const size_t OFF_EX_B  = OFF_P_B + 262144ull;   // 16,384 B (exf[1024]+exb[1024])
static const size_t OFF_CTR_B = OFF_EX_B + 16384ull;   // 256 B
static const size_t NEED_B    = OFF_CTR_B + 256ull;    // ~102.3 MB

// =====================================================================
// Fused producer/consumer kernel. 256 blocks x 256 threads, cooperative.
// Blocks 0..63: recurrence (dir = bid>>5, g = bid&31), all 16384 steps.
// Blocks 64..255: input GEMM, 16 chunks of 1024 t-rows into a 2-deep
// parity ring per direction; sync via gemm_done/recur_prog counters.
// =====================================================================
__global__ __launch_bounds__(256, 1) void fused_kernel(
    const float* __restrict__ seq,
    const float* __restrict__ wih_f, const float* __restrict__ bih_f, const float* __restrict__ bhh_f,
    const float* __restrict__ wih_b, const float* __restrict__ bih_b, const float* __restrict__ bhh_b,
    const float* __restrict__ whh_f, const float* __restrict__ whh_b,
    const float* __restrict__ h0, const float* __restrict__ c0,
    float* __restrict__ hf, float* __restrict__ hb,
    float* __restrict__ Zbuf,
    unsigned long long* __restrict__ exf, unsigned long long* __restrict__ exb,
    unsigned int* __restrict__ gemm_done, unsigned int* __restrict__ recur_prog)
{
    const int bid = blockIdx.x;
    const int tid = threadIdx.x;

    if (bid < 64) {
        // ---------------- recurrence role ----------------
        const int dir = bid >> 5;
        const int g   = bid & 31;
        const float* whh = dir ? whh_b : whh_f;
        float* hout      = dir ? hb : hf;
        unsigned long long* ex = dir ? exb : exf;

        const int w = tid >> 6, lane = tid & 63;
        const int G = lane >> 4, u = lane & 15;
        const int R = 512 * G + 16 * g + u;     // gate row owned by (this lane, wave0 phase)

        // wave w holds K-chunk [128w,128w+128) of gate row R in regs
        float wreg[128];
        {
            const float* src = &whh[(size_t)R * HID + w * 128];
            #pragma unroll
            for (int j = 0; j < 32; ++j) {
                float4 v = *(const float4*)&src[j * 4];
                wreg[j*4+0]=v.x; wreg[j*4+1]=v.y; wreg[j*4+2]=v.z; wreg[j*4+3]=v.w;
            }
        }

        __shared__ __align__(16) float h_lds[512];      // wave-private 128-slices
        __shared__ __align__(16) float p_lds[2][256];   // parity double-buffer

        float cst = 0.f;
        if (w == 0 && lane < 16) cst = c0[dir * HID + 16 * g + lane];

        {   // step-0 h comes from h0; each wave fills its own slice
            const int i0 = 128 * w + 2 * lane;
            h_lds[i0]     = h0[dir * HID + i0];
            h_lds[i0 + 1] = h0[dir * HID + i0 + 1];
        }

        int dead = 0;
        const float* Zd = Zbuf + (size_t)dir * 2 * CSTEPS * G4;

        for (int s = 0; s < T_STEPS; ++s) {
            if ((s & (CSTEPS - 1)) == 0) {      // chunk gate: Z ready?
                if (tid == 0) {
                    const int cg = s >> 10;
                    int guard = 0; unsigned int gd;
                    do {
                        gd = __hip_atomic_load(&gemm_done[cg], __ATOMIC_RELAXED,
                                               __HIP_MEMORY_SCOPE_AGENT);
                        if (++guard > (1 << 20)) { dead = 1; break; }
                    } while (gd < (unsigned)NGEMMB);
                }
                if (__syncthreads_or(dead)) break;
            }
            const int c   = s >> 10;
            const int par = s & 1;
            const int t   = dir ? (T_STEPS - 1 - s) : s;
            const int rr  = dir ? (1023 - (s & 1023)) : (s & 1023);

            float zr = 0.f;                     // issue Z row read early (MALL, fresh)
            if (w == 0)
                zr = __hip_atomic_load(&Zd[((size_t)(c & 1) * CSTEPS + rr) * G4 + R],
                                       __ATOMIC_RELAXED, __HIP_MEMORY_SCOPE_AGENT);

            if (s > 0) {                        // per-wave poll of own 128-slice
                const unsigned long long want = (unsigned long long)(unsigned)s;
                const int i0 = 128 * w + 2 * lane;
                unsigned long long v0, v1;
                int guard = 0;
                for (;;) {
                    v0 = __hip_atomic_load(&ex[par*512 + i0],     __ATOMIC_RELAXED, __HIP_MEMORY_SCOPE_AGENT);
                    v1 = __hip_atomic_load(&ex[par*512 + i0 + 1], __ATOMIC_RELAXED, __HIP_MEMORY_SCOPE_AGENT);
                    if (((v0 >> 32) == want) & ((v1 >> 32) == want)) break;
                    if (++guard > (1 << 16)) { dead = 1; break; }
                }
                union { unsigned int ui; float f; } ca, cb;
                ca.ui = (unsigned int)v0; cb.ui = (unsigned int)v1;
                h_lds[i0]     = ca.f;           // wave-local write->read (lockstep-safe)
                h_lds[i0 + 1] = cb.f;
            }

            float acc = 0.f;
            {
                const float4* h4 = (const float4*)&h_lds[w * 128];
                #pragma unroll
                for (int j = 0; j < 32; ++j) {
                    float4 hv = h4[j];
                    acc += wreg[j*4+0]*hv.x + wreg[j*4+1]*hv.y
                         + wreg[j*4+2]*hv.z + wreg[j*4+3]*hv.w;
                }
            }
            p_lds[par][tid] = acc;
            if (__syncthreads_or(dead)) break;  // the ONLY per-step barrier

            if (w == 0) {
                float rv = p_lds[par][lane] + p_lds[par][64+lane]
                         + p_lds[par][128+lane] + p_lds[par][192+lane] + zr;
                // distributed nonlinearity: each lane does ONE transcendental chain
                float a = (G == 2) ? tanhf(rv) : 1.f / (1.f + expf(-rv));
                float ig = __shfl(a, u,      64);
                float fg = __shfl(a, u + 16, 64);
                float gg = __shfl(a, u + 32, 64);
                float og = __shfl(a, u + 48, 64);
                if (lane < 16) {
                    float cn = fg * cst + ig * gg;
                    cst = cn;
                    float hn = og * tanhf(cn);
                    union { float f; unsigned int ui; } cv; cv.f = hn;
                    __hip_atomic_store(&ex[((s + 1) & 1) * 512 + 16 * g + lane],
                        ((unsigned long long)(unsigned)(s + 1) << 32) | (unsigned long long)cv.ui,
                        __ATOMIC_RELAXED, __HIP_MEMORY_SCOPE_AGENT);   // publish FIRST
                    hout[(size_t)t * HID + 16 * g + lane] = hn;
                }
                if ((s & (CSTEPS - 1)) == (CSTEPS - 1) && lane == 0)
                    __hip_atomic_fetch_add(&recur_prog[c], 1u, __ATOMIC_RELAXED,
                                           __HIP_MEMORY_SCOPE_AGENT);
            }
        }
    } else {
        // ---------------- GEMM producer role ----------------
        const int gb = bid - 64;    // 0..191
        __shared__ __align__(16) float As[16][68];
        __shared__ __align__(16) float Bs[16][68];
        const int lr = tid >> 2, ls = tid & 3, tx = tid & 15, ty = tid >> 4;

        for (int cc = 0; cc < NCHUNK; ++cc) {
            if (cc >= 2 && tid == 0) {          // backpressure: don't overwrite live ring slot
                int guard = 0; unsigned int rp;
                do {
                    rp = __hip_atomic_load(&recur_prog[cc - 2], __ATOMIC_RELAXED,
                                           __HIP_MEMORY_SCOPE_AGENT);
                    if (++guard > (1 << 20)) break;
                } while (rp < 64u);
            }
            __syncthreads();

            for (int tix = gb; tix < 2 * 16 * 32; tix += NGEMMB) {
                const int dr  = tix >> 9;
                const int rem = tix & 511;
                const int mt  = rem >> 5;       // 0..15 t-tile
                const int nt  = rem & 31;       // 0..31 gate-col tile
                const int t0  = dr ? (T_STEPS - (cc + 1) * CSTEPS) : (cc * CSTEPS);
                const float* W  = dr ? wih_b : wih_f;
                const float* bi = dr ? bih_b : bih_f;
                const float* bh = dr ? bhh_b : bhh_f;
                float* Zt = Zbuf + (size_t)(dr * 2 + (cc & 1)) * CSTEPS * G4;

                float acc[4][4] = {};
                for (int k0 = 0; k0 < DMODEL; k0 += 16) {
                    float4 av = *(const float4*)&seq[(size_t)(t0 + mt*64 + lr) * DMODEL + k0 + ls*4];
                    float4 bv = *(const float4*)&W[(size_t)(nt*64 + lr) * DMODEL + k0 + ls*4];
                    __syncthreads();
                    As[ls*4+0][lr]=av.x; As[ls*4+1][lr]=av.y; As[ls*4+2][lr]=av.z; As[ls*4+3][lr]=av.w;
                    Bs[ls*4+0][lr]=bv.x; Bs[ls*4+1][lr]=bv.y; Bs[ls*4+2][lr]=bv.z; Bs[ls*4+3][lr]=bv.w;
                    __syncthreads();
                    #pragma unroll
                    for (int k = 0; k < 16; ++k) {
                        float4 a = *(const float4*)&As[k][ty * 4];
                        float4 b = *(const float4*)&Bs[k][tx * 4];
                        acc[0][0]+=a.x*b.x; acc[0][1]+=a.x*b.y; acc[0][2]+=a.x*b.z; acc[0][3]+=a.x*b.w;
                        acc[1][0]+=a.y*b.x; acc[1][1]+=a.y*b.y; acc[1][2]+=a.y*b.z; acc[1][3]+=a.y*b.w;
                        acc[2][0]+=a.z*b.x; acc[2][1]+=a.z*b.y; acc[2][2]+=a.z*b.z; acc[2][3]+=a.z*b.w;
                        acc[3][0]+=a.w*b.x; acc[3][1]+=a.w*b.y; acc[3][2]+=a.w*b.z; acc[3][3]+=a.w*b.w;
                    }
                }
                float4 b4  = *(const float4*)&bi[nt * 64 + tx * 4];
                float4 c4v = *(const float4*)&bh[nt * 64 + tx * 4];
                float bx=b4.x+c4v.x, by=b4.y+c4v.y, bz=b4.z+c4v.z, bw_=b4.w+c4v.w;
                #pragma unroll
                for (int i = 0; i < 4; ++i) {
                    float4 o;
                    o.x=acc[i][0]+bx; o.y=acc[i][1]+by; o.z=acc[i][2]+bz; o.w=acc[i][3]+bw_;
                    *(float4*)&Zt[(size_t)(mt*64 + ty*4 + i) * G4 + nt*64 + tx*4] = o;
                }
            }
            __threadfence();                    // write back Z before signaling
            __syncthreads();
            if (tid == 0)
                __hip_atomic_fetch_add(&gemm_done[cc], 1u, __ATOMIC_RELEASE,
                                       __HIP_MEMORY_SCOPE_AGENT);
        }
    }
}

// =====================================================================
// feats[t][c] = dot(hf[t]||hb[t], w_lin[c]) + b_lin[c]
// =====================================================================
__global__ __launch_bounds__(256) void feats_kernel(
    const float* __restrict__ hf, const float* __restrict__ hb,
    const float* __restrict__ wlin, const float* __restrict__ blin,
    float* __restrict__ feats)
{
    const int t = blockIdx.x;
    __shared__ __align__(16) float hl[1024];
    const int tid = threadIdx.x;
    {
        const float* src = (tid < 128) ? &hf[(size_t)t * HID + tid * 4]
                                       : &hb[(size_t)t * HID + (tid - 128) * 4];
        *(float4*)&hl[tid * 4] = *(const float4*)src;
    }
    __syncthreads();
    const int c = tid >> 4, p = tid & 15;
    float s = 0.0f;
    #pragma unroll
    for (int j = 0; j < 16; ++j) {
        float4 h4 = *(const float4*)&hl[p * 4 + j * 64];
        float4 w4 = *(const float4*)&wlin[(size_t)c * 1024 + p * 4 + j * 64];
        s += h4.x*w4.x + h4.y*w4.y + h4.z*w4.z + h4.w*w4.w;
    }
    s += __shfl_down(s, 8, 16);
    s += __shfl_down(s, 4, 16);
    s += __shfl_down(s, 2, 16);
    s += __shfl_down(s, 1, 16);
    if (p == 0) feats[t * NC + c] = s + blin[c];
}

// =====================================================================
// Viterbi forward, single wave; fv in registers, shfl broadcast.
// =====================================================================
__global__ __launch_bounds__(64) void viterbi_kernel(
    const float* __restrict__ feats, const float* __restrict__ trans,
    unsigned char* __restrict__ bp, float* __restrict__ out,
    unsigned int* __restrict__ bT)
{
    __shared__ __align__(16) float fl[4096];
    __shared__ __align__(16) float fvs[16];
    const int l = threadIdx.x;
    float tr[16];
    if (l < 16) {
        #pragma unroll
        for (int j = 0; j < 16; ++j) tr[j] = trans[l * 16 + j];
    }
    float fv = 0.0f;
    for (int cb = 0; cb < 64; ++cb) {
        #pragma unroll
        for (int j = 0; j < 16; ++j)
            *(float4*)&fl[j * 256 + l * 4] =
                *(const float4*)&feats[cb * 4096 + j * 256 + l * 4];
        __syncthreads();
        if (l < 16) {
            for (int k = 0; k < 256; ++k) {
                float m = __shfl(fv, 0, 16) + tr[0];
                int bi = 0;
                #pragma unroll
                for (int j = 1; j < 16; ++j) {
                    float sc = __shfl(fv, j, 16) + tr[j];
                    if (sc > m) { m = sc; bi = j; }   // strict > = first max (np.argmax)
                }
                bp[(size_t)(cb * 256 + k) * 16 + l] = (unsigned char)bi;
                fv = m + fl[k * 16 + l];
            }
        }
        __syncthreads();
    }
    if (l < 16) fvs[l] = fv;
    __syncthreads();
    if (l == 0) {
        float best = fvs[0]; int bi = 0;
        #pragma unroll
        for (int j = 1; j < 16; ++j) if (fvs[j] > best) { best = fvs[j]; bi = j; }
        out[0] = best;
        out[1 + T_STEPS] = (float)bi;
        *bT = (unsigned int)bi;
    }
}

// =====================================================================
// per-block composed backpointer maps: P[j][k][s]
// =====================================================================
__global__ __launch_bounds__(64) void maps_kernel(
    const unsigned char* __restrict__ bp, unsigned char* __restrict__ P)
{
    const int j = blockIdx.x;
    const int l = threadIdx.x;
    __shared__ __align__(16) unsigned char lb[4096];
    __shared__ __align__(16) unsigned char lp[4096];
    #pragma unroll
    for (int i = 0; i < 4; ++i)
        *(uint4*)&lb[i * 1024 + l * 16] = *(const uint4*)&bp[(size_t)j * 4096 + i * 1024 + l * 16];
    __syncthreads();
    if (l < 16) {
        int cur = l;
        for (int k = 255; k >= 0; --k) {
            cur = lb[k * 16 + cur];
            lp[k * 16 + l] = (unsigned char)cur;
        }
    }
    __syncthreads();
    #pragma unroll
    for (int i = 0; i < 4; ++i)
        *(uint4*)&P[(size_t)j * 4096 + i * 1024 + l * 16] = *(const uint4*)&lp[i * 1024 + l * 16];
}

// =====================================================================
// stitch + write path as float
// =====================================================================
__global__ __launch_bounds__(64) void path_kernel(
    const unsigned char* __restrict__ P, const unsigned int* __restrict__ bT,
    float* __restrict__ out)
{
    const int j = blockIdx.x;
    const int l = threadIdx.x;
    int e = (int)(*bT);
    for (int i = 63; i > j; --i) e = P[(size_t)i * 4096 + e];
    for (int k = l; k < 256; k += 64)
        out[1 + j * 256 + k] = (float)P[(size_t)j * 4096 + k * 16 + e];
}

__global__ void fb_kernel(float* out, int n, float v0) {
    int i = blockIdx.x * 256 + threadIdx.x;
    if (i < n) out[i] = (i == 0) ? v0 : 0.0f;
}

extern "C" void kernel_launch(void* const* d_in, const int* in_sizes, int n_in,
                              void* d_out, int out_size, void* d_ws, size_t ws_size,
                              hipStream_t stream) {
    const float* seq   = (const float*)d_in[0];
    const float* h0    = (const float*)d_in[1];
    const float* c0    = (const float*)d_in[2];
    const float* wih_f = (const float*)d_in[3];
    const float* whh_f = (const float*)d_in[4];
    const float* bih_f = (const float*)d_in[5];
    const float* bhh_f = (const float*)d_in[6];
    const float* wih_b = (const float*)d_in[7];
    const float* whh_b = (const float*)d_in[8];
    const float* bih_b = (const float*)d_in[9];
    const float* bhh_b = (const float*)d_in[10];
    const float* wlin  = (const float*)d_in[11];
    const float* blin  = (const float*)d_in[12];
    const float* trans = (const float*)d_in[13];
    float* out = (float*)d_out;

    if (ws_size < NEED_B) {
        fb_kernel<<<(out_size + 255) / 256, 256, 0, stream>>>(out, out_size, -(float)ws_size);
        return;
    }

    float* wsf = (float*)d_ws;
    float* Zbuf  = wsf + OFF_Z;
    float* hf    = wsf + OFF_HF;
    float* hb    = wsf + OFF_HB;
    float* feats = wsf + OFF_FEATS;
    unsigned char* bp = (unsigned char*)d_ws + OFF_BP_B;
    unsigned char* P  = (unsigned char*)d_ws + OFF_P_B;
    unsigned long long* exf = (unsigned long long*)((char*)d_ws + OFF_EX_B);
    unsigned long long* exb = exf + 1024;
    unsigned int* ctr = (unsigned int*)((char*)d_ws + OFF_CTR_B);
    unsigned int* gemm_done  = ctr;        // [16]
    unsigned int* recur_prog = ctr + 16;   // [16]
    unsigned int* bT         = ctr + 32;

    // zero exchange tags + counters every call (determinism across replays)
    hipMemsetAsync((void*)exf, 0, 16384 + 256, stream);

    {
        void* args[] = { (void*)&seq,
                         (void*)&wih_f, (void*)&bih_f, (void*)&bhh_f,
                         (void*)&wih_b, (void*)&bih_b, (void*)&bhh_b,
                         (void*)&whh_f, (void*)&whh_b,
                         (void*)&h0, (void*)&c0,
                         (void*)&hf, (void*)&hb, (void*)&Zbuf,
                         (void*)&exf, (void*)&exb,
                         (void*)&gemm_done, (void*)&recur_prog };
        hipError_t e = hipLaunchCooperativeKernel(
            reinterpret_cast<void*>(fused_kernel), dim3(256), dim3(256),
            args, 0, stream);
        if (e != hipSuccess) {
            fused_kernel<<<256, 256, 0, stream>>>(
                seq, wih_f, bih_f, bhh_f, wih_b, bih_b, bhh_b,
                whh_f, whh_b, h0, c0, hf, hb, Zbuf, exf, exb,
                gemm_done, recur_prog);
        }
    }

    feats_kernel<<<16384, 256, 0, stream>>>(hf, hb, wlin, blin, feats);
    viterbi_kernel<<<1, 64, 0, stream>>>(feats, trans, bp, out, bT);
    maps_kernel<<<64, 64, 0, stream>>>(bp, P);
    path_kernel<<<64, 64, 0, stream>>>(P, bT, out);
}